// Round 1
// baseline (232.016 us; speedup 1.0000x reference)
//
#include <hip/hip_runtime.h>
#include <hip/hip_bf16.h>
#include <math.h>

#define NTOT  8192
#define DIM   512
#define BATCH (NTOT/2)
#define TEMP_INV 5.0f   // 1/0.2
#define TTILE 64                      // 8192 / 128 tiles per side
#define NBLK  (TTILE*(TTILE+1)/2)     // 2080 upper-triangle tiles

typedef __attribute__((ext_vector_type(8))) short bf16x8;
typedef __attribute__((ext_vector_type(4))) float f32x4;

__device__ __forceinline__ float b2f(unsigned short u)
{
    unsigned int x = (unsigned int)u << 16;
    float f; __builtin_memcpy(&f, &x, 4); return f;
}

// column-major triangle decode: t = bj*(bj+1)/2 + bi, bi <= bj.
__device__ __forceinline__ void decode_tile(int t, int& bi, int& bj)
{
    int b = (int)((sqrtf(8.0f * (float)t + 1.0f) - 1.0f) * 0.5f);
    while ((b + 1) * (b + 2) / 2 <= t) ++b;
    while (b * (b + 1) / 2 > t)       --b;
    bj = b;
    bi = t - b * (b + 1) / 2;
}

__device__ __forceinline__ unsigned int pack_bf16_2(float a, float b)
{
    __hip_bfloat16 ha = __float2bfloat16(a), hb = __float2bfloat16(b);
    unsigned short ua, ub;
    __builtin_memcpy(&ua, &ha, 2); __builtin_memcpy(&ub, &hb, 2);
    return (unsigned int)ua | ((unsigned int)ub << 16);
}

// ---------------- normalize: one wave per row ----------------
__global__ __launch_bounds__(256)
void normalize_k(const float* __restrict__ z, __hip_bfloat16* __restrict__ zn)
{
    const int lane = threadIdx.x & 63, wave = threadIdx.x >> 6;
    const int row  = blockIdx.x * 4 + wave;
    const float4* zr = (const float4*)(z + (size_t)row * DIM);
    const float4 a = zr[lane];
    const float4 b = zr[lane + 64];
    float ss = a.x*a.x + a.y*a.y + a.z*a.z + a.w*a.w
             + b.x*b.x + b.y*b.y + b.z*b.z + b.w*b.w;
    #pragma unroll
    for (int off = 1; off < 64; off <<= 1) ss += __shfl_xor(ss, off);
    const float inv = 1.0f / fmaxf(sqrtf(ss), 1e-12f);
    uint2* zo = (uint2*)(zn + (size_t)row * DIM);
    uint2 o0, o1;
    o0.x = pack_bf16_2(a.x * inv, a.y * inv);
    o0.y = pack_bf16_2(a.z * inv, a.w * inv);
    o1.x = pack_bf16_2(b.x * inv, b.y * inv);
    o1.y = pack_bf16_2(b.z * inv, b.w * inv);
    zo[lane]      = o0;
    zo[lane + 64] = o1;
}

// ---------------- transpose zn -> znT [512][8192], fused column sums S ----------------
__global__ __launch_bounds__(256)
void transpose_colsum_k(const __hip_bfloat16* __restrict__ zn,
                        __hip_bfloat16* __restrict__ znT,
                        float* __restrict__ S)
{
    __shared__ unsigned short T[64][72];   // 72-short row stride = 144 B (16 B aligned)
    __shared__ float Scol[64];
    const int tid = threadIdx.x;
    const int bs = blockIdx.x & 127;       // sample tile (8192/64)
    const int bd = blockIdx.x >> 7;        // dim tile (512/64)
    const int s0 = bs * 64, d0 = bd * 64;
    if (tid < 64) Scol[tid] = 0.f;
    const int rr = tid >> 3;               // 0..31
    const int c8 = (tid & 7) * 8;          // 0,8,..,56
    float part[8];
    #pragma unroll
    for (int j = 0; j < 8; ++j) part[j] = 0.f;
    #pragma unroll
    for (int h = 0; h < 2; ++h) {
        const int row = rr + h * 32;
        const bf16x8 v = *(const bf16x8*)(zn + (size_t)(s0 + row) * DIM + d0 + c8);
        *(bf16x8*)&T[row][c8] = v;
        #pragma unroll
        for (int j = 0; j < 8; ++j) part[j] += b2f((unsigned short)v[j]);
    }
    __syncthreads();
    #pragma unroll
    for (int h = 0; h < 2; ++h) {
        const int d = rr + h * 32;
        bf16x8 ov;
        #pragma unroll
        for (int j = 0; j < 8; ++j) ov[j] = (short)T[c8 + j][d];
        *(bf16x8*)(znT + (size_t)(d0 + d) * NTOT + s0 + c8) = ov;
    }
    #pragma unroll
    for (int j = 0; j < 8; ++j) atomicAdd(&Scol[c8 + j], part[j]);
    __syncthreads();
    if (tid < 64) atomicAdd(&S[d0 + tid], Scol[tid]);
}

// ---------------- rowsum_i = zn_i . S  (= sum_j sim_ij) ----------------
__global__ __launch_bounds__(256)
void rowsum_k(const __hip_bfloat16* __restrict__ zn,
              const float* __restrict__ S,
              float* __restrict__ rowsum)
{
    const int lane = threadIdx.x & 63, wave = threadIdx.x >> 6;
    const int row = blockIdx.x * 4 + wave;
    const bf16x8 v = *(const bf16x8*)(zn + (size_t)row * DIM + lane * 8);
    const float4 sa = *(const float4*)(S + lane * 8);
    const float4 sb = *(const float4*)(S + lane * 8 + 4);
    float acc = b2f((unsigned short)v[0]) * sa.x + b2f((unsigned short)v[1]) * sa.y
              + b2f((unsigned short)v[2]) * sa.z + b2f((unsigned short)v[3]) * sa.w
              + b2f((unsigned short)v[4]) * sb.x + b2f((unsigned short)v[5]) * sb.y
              + b2f((unsigned short)v[6]) * sb.z + b2f((unsigned short)v[7]) * sb.w;
    #pragma unroll
    for (int off = 1; off < 64; off <<= 1) acc += __shfl_xor(acc, off);
    if (lane == 0) rowsum[row] = acc;
}

// ---------------- shared MFMA K-loop: 128x128 tile, K=512, BK=32 ----------------
// LDS: 3-stage ring, 2-deep prefetch, counted vmcnt, ONE barrier per K-step.
// Stage layout (verified): seg s holds rows s*16..s*16+15; slot l -> (row s*16+(l&15), k (l>>4)*8).
__device__ __forceinline__ void issue4(const __hip_bfloat16* A, int sA,
                                       const __hip_bfloat16* B, int sB,
                                       int gk, unsigned short* Ad, unsigned short* Bd,
                                       int wave, int lane)
{
    const int f_l = lane & 15, q_l = lane >> 4;
    #pragma unroll
    for (int q = 0; q < 2; ++q) {
        const int s = wave * 2 + q;
        const __hip_bfloat16* ga = A + (size_t)(s * 16 + f_l) * sA + gk + q_l * 8;
        const __hip_bfloat16* gb = B + (size_t)(s * 16 + f_l) * sB + gk + q_l * 8;
        __builtin_amdgcn_global_load_lds(
            (const __attribute__((address_space(1))) unsigned int*)ga,
            (__attribute__((address_space(3))) unsigned int*)(Ad + s * 512 + lane * 8),
            16, 0, 0);
        __builtin_amdgcn_global_load_lds(
            (const __attribute__((address_space(1))) unsigned int*)gb,
            (__attribute__((address_space(3))) unsigned int*)(Bd + s * 512 + lane * 8),
            16, 0, 0);
    }
}

__device__ __forceinline__ void mm_kloop16(const __hip_bfloat16* A, int sA,
                                           const __hip_bfloat16* B, int sB,
                                           unsigned short (*As)[4096],
                                           unsigned short (*Bs)[4096],
                                           f32x4 acc[4][4], int wave, int lane)
{
    const int wr = wave >> 1, wc = wave & 1;
    issue4(A, sA, B, sB, 0,  As[0], Bs[0], wave, lane);
    issue4(A, sA, B, sB, 32, As[1], Bs[1], wave, lane);
    #pragma unroll
    for (int ki = 0; ki < 16; ++ki) {
        // Wait: my 4 loads for buf[ki%3] done (they are the oldest); next buf's 4 stay in flight.
        // Barrier then guarantees ALL waves' loads for this buf landed, and all waves
        // finished reading buf[(ki-1)%3] == buf[(ki+2)%3] -> safe to re-target it below.
        if (ki < 15) asm volatile("s_waitcnt vmcnt(4)\n\ts_barrier" ::: "memory");
        else         asm volatile("s_waitcnt vmcnt(0)\n\ts_barrier" ::: "memory");
        __builtin_amdgcn_sched_barrier(0);
        if (ki + 2 < 16)
            issue4(A, sA, B, sB, (ki + 2) * 32, As[(ki + 2) % 3], Bs[(ki + 2) % 3], wave, lane);
        const unsigned short* Ap = As[ki % 3];
        const unsigned short* Bp = Bs[ki % 3];
        bf16x8 af[4], bfr[4];
        #pragma unroll
        for (int r = 0; r < 4; ++r)
            af[r] = *(const bf16x8*)(Ap + (wr * 4 + r) * 512 + lane * 8);
        #pragma unroll
        for (int c = 0; c < 4; ++c)
            bfr[c] = *(const bf16x8*)(Bp + (wc * 4 + c) * 512 + lane * 8);
        #pragma unroll
        for (int r = 0; r < 4; ++r)
            #pragma unroll
            for (int c = 0; c < 4; ++c)
                acc[r][c] = __builtin_amdgcn_mfma_f32_16x16x32_bf16(af[r], bfr[c], acc[r][c], 0, 0, 0);
    }
}

// ---------------- Gram: G = znT . znT^T = zn^T zn, f32 atomics ----------------
__global__ __launch_bounds__(256, 3)
void gram_k(const __hip_bfloat16* __restrict__ znT, float* __restrict__ Gf32)
{
    __shared__ unsigned short As[3][4096];
    __shared__ unsigned short Bs[3][4096];
    const int tid = threadIdx.x, wave = tid >> 6, lane = tid & 63;
    const int f_l = lane & 15, q_l = lane >> 4;
    const int t = blockIdx.x & 15, ch = blockIdx.x >> 4;     // 16 tiles x 16 K-chunks
    const int di = (t >> 2) * 128, dj = (t & 3) * 128;
    const int wr = wave >> 1, wc = wave & 1;
    f32x4 acc[4][4];
    #pragma unroll
    for (int r = 0; r < 4; ++r)
        #pragma unroll
        for (int c = 0; c < 4; ++c) acc[r][c] = (f32x4){0.f, 0.f, 0.f, 0.f};
    mm_kloop16(znT + (size_t)di * NTOT + ch * 512, NTOT,
               znT + (size_t)dj * NTOT + ch * 512, NTOT, As, Bs, acc, wave, lane);
    #pragma unroll
    for (int r = 0; r < 4; ++r)
        #pragma unroll
        for (int c = 0; c < 4; ++c)
            #pragma unroll
            for (int u = 0; u < 4; ++u) {
                const int row = di + wr * 64 + r * 16 + q_l * 4 + u;
                const int col = dj + wc * 64 + c * 16 + f_l;
                atomicAdd(&Gf32[row * 512 + col], acc[r][c][u]);
            }
}

// ---------------- G f32 -> bf16 (G symmetric, rows usable as B-operand) ----------------
__global__ __launch_bounds__(256)
void gram_fin_k(const float* __restrict__ Gf32, __hip_bfloat16* __restrict__ G1)
{
    const int i = (blockIdx.x * 256 + threadIdx.x) * 4;
    const float4 v = *(const float4*)(Gf32 + i);
    uint2 o;
    o.x = pack_bf16_2(v.x, v.y);
    o.y = pack_bf16_2(v.z, v.w);
    *(uint2*)(G1 + i) = o;
}

// ---------------- rowsumsq_i = zn_i G zn_i^T via H = zn.G, fused reduce ----------------
__global__ __launch_bounds__(256, 3)
void rowstats_k(const __hip_bfloat16* __restrict__ zn,
                const __hip_bfloat16* __restrict__ G1,
                float* __restrict__ rowsumsq)
{
    __shared__ unsigned short As[3][4096];
    __shared__ unsigned short Bs[3][4096];
    const int tid = threadIdx.x, wave = tid >> 6, lane = tid & 63;
    const int f_l = lane & 15, q_l = lane >> 4;
    const int R0 = (blockIdx.x >> 2) * 128, C0 = (blockIdx.x & 3) * 128;
    const int wr = wave >> 1, wc = wave & 1;
    f32x4 acc[4][4];
    #pragma unroll
    for (int r = 0; r < 4; ++r)
        #pragma unroll
        for (int c = 0; c < 4; ++c) acc[r][c] = (f32x4){0.f, 0.f, 0.f, 0.f};
    mm_kloop16(zn + (size_t)R0 * DIM, DIM, G1 + (size_t)C0 * DIM, DIM, As, Bs, acc, wave, lane);
    // rowsumsq partial: sum_c H[i][c] * zn[i][c] over this block's 128 cols
    #pragma unroll
    for (int r = 0; r < 4; ++r) {
        #pragma unroll
        for (int u = 0; u < 4; ++u) {
            const int i = R0 + wr * 64 + r * 16 + q_l * 4 + u;
            float p = 0.f;
            #pragma unroll
            for (int c = 0; c < 4; ++c) {
                const int col = C0 + wc * 64 + c * 16 + f_l;
                unsigned short zb;
                __builtin_memcpy(&zb, zn + (size_t)i * DIM + col, 2);
                p += acc[r][c][u] * b2f(zb);
            }
            p += __shfl_xor(p, 1); p += __shfl_xor(p, 2);
            p += __shfl_xor(p, 4); p += __shfl_xor(p, 8);
            if (f_l == 0) atomicAdd(&rowsumsq[i], p);
        }
    }
}

// ---------------- stats finalize ----------------
__global__ void finalize_stats_k(const float* __restrict__ rowsum,
                                 const float* __restrict__ rowsumsq,
                                 float* __restrict__ mu_d,
                                 float* __restrict__ inv2s2)
{
    const int j = blockIdx.x * blockDim.x + threadIdx.x;
    if (j < NTOT) {
        const float s  = rowsum[j];
        const float sq = rowsumsq[j];
        const float mean_sim = s * (1.0f / NTOT);
        const float var = (sq - s * mean_sim) * (1.0f / (NTOT - 1));
        mu_d[j]   = 1.0f - mean_sim;
        inv2s2[j] = 1.0f / (2.0f * var);
    }
}

// ---------------- single fused pass: triangle GEMM + exp epilogue ----------------
__global__ __launch_bounds__(256, 3)
void sim_neg_k(const __hip_bfloat16* __restrict__ zn,
               const int*   __restrict__ labels,
               const float* __restrict__ mu_d,
               const float* __restrict__ inv2s2,
               double* __restrict__ neg_acc)
{
    __shared__ unsigned short As[3][4096];
    __shared__ unsigned short Bs[3][4096];
    __shared__ float redbuf[4];
    const int tid = threadIdx.x, wave = tid >> 6, lane = tid & 63;
    const int f_l = lane & 15, q_l = lane >> 4;
    int bi, bj;
    decode_tile(blockIdx.x, bi, bj);
    const int R0 = bi * 128, C0 = bj * 128;
    const int wr = wave >> 1, wc = wave & 1;
    f32x4 acc[4][4];
    #pragma unroll
    for (int r = 0; r < 4; ++r)
        #pragma unroll
        for (int c = 0; c < 4; ++c) acc[r][c] = (f32x4){0.f, 0.f, 0.f, 0.f};
    mm_kloop16(zn + (size_t)R0 * DIM, DIM, zn + (size_t)C0 * DIM, DIM, As, Bs, acc, wave, lane);

    // fused exp epilogue (each stored element covers full-matrix entries (j,i) [j-stats]
    // and, for off-diag tiles, (i,j) [i-stats]; diag tiles hold both orders themselves)
    int labj[4]; float muj[4], isj[4];
    #pragma unroll
    for (int c = 0; c < 4; ++c) {
        const int j = C0 + wc * 64 + c * 16 + f_l;
        labj[c] = labels[j]; muj[c] = mu_d[j]; isj[c] = inv2s2[j];
    }
    float local = 0.f;
    #pragma unroll
    for (int r = 0; r < 4; ++r) {
        const int ib = R0 + wr * 64 + r * 16 + q_l * 4;
        #pragma unroll
        for (int u = 0; u < 4; ++u) {
            const int   li = labels[ib + u];
            const float mi = mu_d[ib + u];
            const float vi = inv2s2[ib + u];
            #pragma unroll
            for (int c = 0; c < 4; ++c) {
                const float s  = acc[r][c][u];
                const float dj = (1.0f - s) - muj[c];
                float e = __expf(s * TEMP_INV + dj * dj * isj[c]);
                if (bi != bj) {
                    const float di = (1.0f - s) - mi;
                    e += __expf(s * TEMP_INV + di * di * vi);
                }
                local += (li != labj[c]) ? e : 0.f;
            }
        }
    }
    #pragma unroll
    for (int off = 1; off < 64; off <<= 1) local += __shfl_xor(local, off);
    if (lane == 0) redbuf[wave] = local;
    __syncthreads();
    if (tid == 0)
        atomicAdd(neg_acc, (double)(redbuf[0] + redbuf[1] + redbuf[2] + redbuf[3]));
}

// ---------------- positive pairs (vectorized) ----------------
__global__ __launch_bounds__(256)
void pos_k(const __hip_bfloat16* __restrict__ zn, const int* __restrict__ labels,
           double* __restrict__ pos_acc)
{
    const int wave = threadIdx.x >> 6, lane = threadIdx.x & 63;
    const int pair = blockIdx.x * 4 + wave;
    const bf16x8 va = *(const bf16x8*)(zn + (size_t)pair * DIM + lane * 8);
    const bf16x8 vb = *(const bf16x8*)(zn + (size_t)(pair + BATCH) * DIM + lane * 8);
    float s = 0.f;
    #pragma unroll
    for (int j = 0; j < 8; ++j)
        s += b2f((unsigned short)va[j]) * b2f((unsigned short)vb[j]);
    #pragma unroll
    for (int off = 1; off < 64; off <<= 1) s += __shfl_xor(s, off);
    if (lane == 0 && labels[pair] == labels[pair + BATCH])
        atomicAdd(pos_acc, (double)__expf(s * TEMP_INV));
}

// ---------------- final loss ----------------
__global__ void loss_k(const double* __restrict__ accs, float* __restrict__ out)
{
    const double neg = accs[0], pos = accs[1];
    out[0] = (float)(-log(pos / (pos + neg)));
}

extern "C" void kernel_launch(void* const* d_in, const int* in_sizes, int n_in,
                              void* d_out, int out_size, void* d_ws, size_t ws_size,
                              hipStream_t stream)
{
    const float* z      = (const float*)d_in[0];
    const int*   labels = (const int*)d_in[1];
    float* out = (float*)d_out;

    char* ws = (char*)d_ws;
    __hip_bfloat16* zn  = (__hip_bfloat16*)ws;                                // 8 MiB
    __hip_bfloat16* znT = (__hip_bfloat16*)(ws + ((size_t)8 << 20));          // 8 MiB
    float*  Gf32     = (float*)(ws + ((size_t)16 << 20));                     // 1 MiB
    float*  S        = Gf32 + 512 * 512;                                      // 2 KiB
    float*  rowsumsq = S + 512;                                               // 32 KiB
    double* accs     = (double*)(rowsumsq + NTOT);                            // 16 B  [0]=neg [1]=pos
    float*  rowsum   = (float*)(accs + 2);                                    // 32 KiB
    float*  mu_d     = rowsum + NTOT;
    float*  inv2s2   = mu_d + NTOT;
    __hip_bfloat16* G1 = (__hip_bfloat16*)(inv2s2 + NTOT);                    // 512 KiB

    // zero: Gf32 + S + rowsumsq + accs (contiguous)
    hipMemsetAsync(Gf32, 0,
                   (size_t)(512 * 512 + 512 + NTOT) * sizeof(float) + 2 * sizeof(double),
                   stream);

    normalize_k<<<NTOT / 4, 256, 0, stream>>>(z, zn);
    transpose_colsum_k<<<1024, 256, 0, stream>>>(zn, znT, S);
    rowsum_k<<<NTOT / 4, 256, 0, stream>>>(zn, S, rowsum);
    gram_k<<<256, 256, 0, stream>>>(znT, Gf32);
    gram_fin_k<<<256, 256, 0, stream>>>(Gf32, G1);
    rowstats_k<<<256, 256, 0, stream>>>(zn, G1, rowsumsq);
    finalize_stats_k<<<NTOT / 256, 256, 0, stream>>>(rowsum, rowsumsq, mu_d, inv2s2);
    sim_neg_k<<<NBLK, 256, 0, stream>>>(zn, labels, mu_d, inv2s2, accs);
    pos_k<<<BATCH / 4, 256, 0, stream>>>(zn, labels, accs + 1);
    loss_k<<<1, 1, 0, stream>>>(accs, out);
}

// Round 2
// 228.084 us; speedup vs baseline: 1.0172x; 1.0172x over previous
//
#include <hip/hip_runtime.h>
#include <hip/hip_bf16.h>
#include <math.h>

#define NTOT  8192
#define DIM   512
#define BATCH (NTOT/2)
#define TEMP_INV 5.0f   // 1/0.2
#define TTILE 64                      // 8192 / 128 tiles per side
#define NBLK  (TTILE*(TTILE+1)/2)     // 2080 upper-triangle tiles

typedef __attribute__((ext_vector_type(8))) short bf16x8;
typedef __attribute__((ext_vector_type(4))) float f32x4;

__device__ __forceinline__ float b2f(unsigned short u)
{
    unsigned int x = (unsigned int)u << 16;
    float f; __builtin_memcpy(&f, &x, 4); return f;
}

// column-major triangle decode: t = bj*(bj+1)/2 + bi, bi <= bj.
__device__ __forceinline__ void decode_tile(int t, int& bi, int& bj)
{
    int b = (int)((sqrtf(8.0f * (float)t + 1.0f) - 1.0f) * 0.5f);
    while ((b + 1) * (b + 2) / 2 <= t) ++b;
    while (b * (b + 1) / 2 > t)       --b;
    bj = b;
    bi = t - b * (b + 1) / 2;
}

__device__ __forceinline__ unsigned int pack_bf16_2(float a, float b)
{
    __hip_bfloat16 ha = __float2bfloat16(a), hb = __float2bfloat16(b);
    unsigned short ua, ub;
    __builtin_memcpy(&ua, &ha, 2); __builtin_memcpy(&ub, &hb, 2);
    return (unsigned int)ua | ((unsigned int)ub << 16);
}

// ---------------- normalize: one wave per row ----------------
__global__ __launch_bounds__(256)
void normalize_k(const float* __restrict__ z, __hip_bfloat16* __restrict__ zn)
{
    const int lane = threadIdx.x & 63, wave = threadIdx.x >> 6;
    const int row  = blockIdx.x * 4 + wave;
    const float4* zr = (const float4*)(z + (size_t)row * DIM);
    const float4 a = zr[lane];
    const float4 b = zr[lane + 64];
    float ss = a.x*a.x + a.y*a.y + a.z*a.z + a.w*a.w
             + b.x*b.x + b.y*b.y + b.z*b.z + b.w*b.w;
    #pragma unroll
    for (int off = 1; off < 64; off <<= 1) ss += __shfl_xor(ss, off);
    const float inv = 1.0f / fmaxf(sqrtf(ss), 1e-12f);
    uint2* zo = (uint2*)(zn + (size_t)row * DIM);
    uint2 o0, o1;
    o0.x = pack_bf16_2(a.x * inv, a.y * inv);
    o0.y = pack_bf16_2(a.z * inv, a.w * inv);
    o1.x = pack_bf16_2(b.x * inv, b.y * inv);
    o1.y = pack_bf16_2(b.z * inv, b.w * inv);
    zo[lane]      = o0;
    zo[lane + 64] = o1;
}

// ---------------- transpose zn -> znT [512][8192], fused column sums S ----------------
__global__ __launch_bounds__(256)
void transpose_colsum_k(const __hip_bfloat16* __restrict__ zn,
                        __hip_bfloat16* __restrict__ znT,
                        float* __restrict__ S)
{
    __shared__ unsigned short T[64][72];   // 72-short row stride = 144 B (16 B aligned)
    __shared__ float Scol[64];
    const int tid = threadIdx.x;
    const int bs = blockIdx.x & 127;       // sample tile (8192/64)
    const int bd = blockIdx.x >> 7;        // dim tile (512/64)
    const int s0 = bs * 64, d0 = bd * 64;
    if (tid < 64) Scol[tid] = 0.f;
    const int rr = tid >> 3;               // 0..31
    const int c8 = (tid & 7) * 8;          // 0,8,..,56
    float part[8];
    #pragma unroll
    for (int j = 0; j < 8; ++j) part[j] = 0.f;
    #pragma unroll
    for (int h = 0; h < 2; ++h) {
        const int row = rr + h * 32;
        const bf16x8 v = *(const bf16x8*)(zn + (size_t)(s0 + row) * DIM + d0 + c8);
        *(bf16x8*)&T[row][c8] = v;
        #pragma unroll
        for (int j = 0; j < 8; ++j) part[j] += b2f((unsigned short)v[j]);
    }
    __syncthreads();
    #pragma unroll
    for (int h = 0; h < 2; ++h) {
        const int d = rr + h * 32;
        bf16x8 ov;
        #pragma unroll
        for (int j = 0; j < 8; ++j) ov[j] = (short)T[c8 + j][d];
        *(bf16x8*)(znT + (size_t)(d0 + d) * NTOT + s0 + c8) = ov;
    }
    #pragma unroll
    for (int j = 0; j < 8; ++j) atomicAdd(&Scol[c8 + j], part[j]);
    __syncthreads();
    if (tid < 64) atomicAdd(&S[d0 + tid], Scol[tid]);
}

// ---------------- shared MFMA K-loop: 128x128 tile, K=512, BK=32 ----------------
// LDS: 3-stage ring, 2-deep prefetch, counted vmcnt, ONE barrier per K-step.
__device__ __forceinline__ void issue4(const __hip_bfloat16* A, int sA,
                                       const __hip_bfloat16* B, int sB,
                                       int gk, unsigned short* Ad, unsigned short* Bd,
                                       int wave, int lane)
{
    const int f_l = lane & 15, q_l = lane >> 4;
    #pragma unroll
    for (int q = 0; q < 2; ++q) {
        const int s = wave * 2 + q;
        const __hip_bfloat16* ga = A + (size_t)(s * 16 + f_l) * sA + gk + q_l * 8;
        const __hip_bfloat16* gb = B + (size_t)(s * 16 + f_l) * sB + gk + q_l * 8;
        __builtin_amdgcn_global_load_lds(
            (const __attribute__((address_space(1))) unsigned int*)ga,
            (__attribute__((address_space(3))) unsigned int*)(Ad + s * 512 + lane * 8),
            16, 0, 0);
        __builtin_amdgcn_global_load_lds(
            (const __attribute__((address_space(1))) unsigned int*)gb,
            (__attribute__((address_space(3))) unsigned int*)(Bd + s * 512 + lane * 8),
            16, 0, 0);
    }
}

__device__ __forceinline__ void mm_kloop16(const __hip_bfloat16* A, int sA,
                                           const __hip_bfloat16* B, int sB,
                                           unsigned short (*As)[4096],
                                           unsigned short (*Bs)[4096],
                                           f32x4 acc[4][4], int wave, int lane)
{
    const int wr = wave >> 1, wc = wave & 1;
    issue4(A, sA, B, sB, 0,  As[0], Bs[0], wave, lane);
    issue4(A, sA, B, sB, 32, As[1], Bs[1], wave, lane);
    #pragma unroll
    for (int ki = 0; ki < 16; ++ki) {
        // Pin all prior work (MFMAs of step ki-1) above the retarget point.
        __builtin_amdgcn_sched_barrier(0);
        // Wait: my 4 loads for buf[ki%3] done; next buf's 4 stay in flight.
        // Barrier then guarantees ALL waves' loads landed AND all waves finished
        // reading buf[(ki-1)%3] == buf[(ki+2)%3] -> safe to re-target it below.
        if (ki < 15) asm volatile("s_waitcnt vmcnt(4)\n\ts_barrier" ::: "memory");
        else         asm volatile("s_waitcnt vmcnt(0)\n\ts_barrier" ::: "memory");
        __builtin_amdgcn_sched_barrier(0);
        if (ki + 2 < 16)
            issue4(A, sA, B, sB, (ki + 2) * 32, As[(ki + 2) % 3], Bs[(ki + 2) % 3], wave, lane);
        const unsigned short* Ap = As[ki % 3];
        const unsigned short* Bp = Bs[ki % 3];
        bf16x8 af[4], bfr[4];
        #pragma unroll
        for (int r = 0; r < 4; ++r)
            af[r] = *(const bf16x8*)(Ap + (wr * 4 + r) * 512 + lane * 8);
        #pragma unroll
        for (int c = 0; c < 4; ++c)
            bfr[c] = *(const bf16x8*)(Bp + (wc * 4 + c) * 512 + lane * 8);
        #pragma unroll
        for (int r = 0; r < 4; ++r)
            #pragma unroll
            for (int c = 0; c < 4; ++c)
                acc[r][c] = __builtin_amdgcn_mfma_f32_16x16x32_bf16(af[r], bfr[c], acc[r][c], 0, 0, 0);
    }
}

// ---------------- Gram: G = znT . znT^T = zn^T zn, per-chunk partials (NO atomics) ----------------
__global__ __launch_bounds__(256, 3)
void gram_k(const __hip_bfloat16* __restrict__ znT, float* __restrict__ Gpart)
{
    __shared__ unsigned short As[3][4096];
    __shared__ unsigned short Bs[3][4096];
    const int tid = threadIdx.x, wave = tid >> 6, lane = tid & 63;
    const int f_l = lane & 15, q_l = lane >> 4;
    const int t = blockIdx.x & 15, ch = blockIdx.x >> 4;     // 16 tiles x 16 K-chunks
    const int di = (t >> 2) * 128, dj = (t & 3) * 128;
    const int wr = wave >> 1, wc = wave & 1;
    f32x4 acc[4][4];
    #pragma unroll
    for (int r = 0; r < 4; ++r)
        #pragma unroll
        for (int c = 0; c < 4; ++c) acc[r][c] = (f32x4){0.f, 0.f, 0.f, 0.f};
    mm_kloop16(znT + (size_t)di * NTOT + ch * 512, NTOT,
               znT + (size_t)dj * NTOT + ch * 512, NTOT, As, Bs, acc, wave, lane);
    float* gp = Gpart + (size_t)ch * (512 * 512);
    #pragma unroll
    for (int r = 0; r < 4; ++r)
        #pragma unroll
        for (int c = 0; c < 4; ++c)
            #pragma unroll
            for (int u = 0; u < 4; ++u) {
                const int row = di + wr * 64 + r * 16 + q_l * 4 + u;
                const int col = dj + wc * 64 + c * 16 + f_l;
                gp[row * 512 + col] = acc[r][c][u];
            }
}

// ---------------- reduce 16 partials -> bf16 G ----------------
__global__ __launch_bounds__(256)
void gram_fin_k(const float* __restrict__ Gpart, __hip_bfloat16* __restrict__ G1)
{
    const int i = (blockIdx.x * 256 + threadIdx.x) * 4;
    float4 s = {0.f, 0.f, 0.f, 0.f};
    #pragma unroll
    for (int ch = 0; ch < 16; ++ch) {
        const float4 v = *(const float4*)(Gpart + (size_t)ch * (512 * 512) + i);
        s.x += v.x; s.y += v.y; s.z += v.z; s.w += v.w;
    }
    uint2 o;
    o.x = pack_bf16_2(s.x, s.y);
    o.y = pack_bf16_2(s.z, s.w);
    *(uint2*)(G1 + i) = o;
}

// ---------------- rowsumsq_i = zn_i G zn_i^T via H = zn.G, fused reduce ----------------
__global__ __launch_bounds__(256, 3)
void rowstats_k(const __hip_bfloat16* __restrict__ zn,
                const __hip_bfloat16* __restrict__ G1,
                float* __restrict__ rowsumsq)
{
    __shared__ unsigned short As[3][4096];
    __shared__ unsigned short Bs[3][4096];
    const int tid = threadIdx.x, wave = tid >> 6, lane = tid & 63;
    const int f_l = lane & 15, q_l = lane >> 4;
    const int R0 = (blockIdx.x >> 2) * 128, C0 = (blockIdx.x & 3) * 128;
    const int wr = wave >> 1, wc = wave & 1;
    f32x4 acc[4][4];
    #pragma unroll
    for (int r = 0; r < 4; ++r)
        #pragma unroll
        for (int c = 0; c < 4; ++c) acc[r][c] = (f32x4){0.f, 0.f, 0.f, 0.f};
    mm_kloop16(zn + (size_t)R0 * DIM, DIM, G1 + (size_t)C0 * DIM, DIM, As, Bs, acc, wave, lane);
    #pragma unroll
    for (int r = 0; r < 4; ++r) {
        #pragma unroll
        for (int u = 0; u < 4; ++u) {
            const int i = R0 + wr * 64 + r * 16 + q_l * 4 + u;
            float p = 0.f;
            #pragma unroll
            for (int c = 0; c < 4; ++c) {
                const int col = C0 + wc * 64 + c * 16 + f_l;
                unsigned short zb;
                __builtin_memcpy(&zb, zn + (size_t)i * DIM + col, 2);
                p += acc[r][c][u] * b2f(zb);
            }
            p += __shfl_xor(p, 1); p += __shfl_xor(p, 2);
            p += __shfl_xor(p, 4); p += __shfl_xor(p, 8);
            if (f_l == 0) atomicAdd(&rowsumsq[i], p);
        }
    }
}

// ---------------- stats finalize, fused rowsum (zn_i . S) ----------------
__global__ __launch_bounds__(256)
void finalize_stats_k(const __hip_bfloat16* __restrict__ zn,
                      const float* __restrict__ S,
                      const float* __restrict__ rowsumsq,
                      float* __restrict__ mu_d,
                      float* __restrict__ inv2s2)
{
    const int lane = threadIdx.x & 63, wave = threadIdx.x >> 6;
    const int row = blockIdx.x * 4 + wave;
    const bf16x8 v = *(const bf16x8*)(zn + (size_t)row * DIM + lane * 8);
    const float4 sa = *(const float4*)(S + lane * 8);
    const float4 sb = *(const float4*)(S + lane * 8 + 4);
    float acc = b2f((unsigned short)v[0]) * sa.x + b2f((unsigned short)v[1]) * sa.y
              + b2f((unsigned short)v[2]) * sa.z + b2f((unsigned short)v[3]) * sa.w
              + b2f((unsigned short)v[4]) * sb.x + b2f((unsigned short)v[5]) * sb.y
              + b2f((unsigned short)v[6]) * sb.z + b2f((unsigned short)v[7]) * sb.w;
    #pragma unroll
    for (int off = 1; off < 64; off <<= 1) acc += __shfl_xor(acc, off);
    if (lane == 0) {
        const float s  = acc;
        const float sq = rowsumsq[row];
        const float mean_sim = s * (1.0f / NTOT);
        const float var = (sq - s * mean_sim) * (1.0f / (NTOT - 1));
        mu_d[row]   = 1.0f - mean_sim;
        inv2s2[row] = 1.0f / (2.0f * var);
    }
}

// ---------------- single fused pass: triangle GEMM + exp epilogue ----------------
__global__ __launch_bounds__(256, 3)
void sim_neg_k(const __hip_bfloat16* __restrict__ zn,
               const int*   __restrict__ labels,
               const float* __restrict__ mu_d,
               const float* __restrict__ inv2s2,
               double* __restrict__ neg_acc)
{
    __shared__ unsigned short As[3][4096];
    __shared__ unsigned short Bs[3][4096];
    __shared__ float redbuf[4];
    const int tid = threadIdx.x, wave = tid >> 6, lane = tid & 63;
    const int f_l = lane & 15, q_l = lane >> 4;
    // chunked XCD swizzle: 2080 % 8 == 0 -> bijective; each XCD gets 260 consecutive tiles
    const int t = (int)(blockIdx.x & 7) * (NBLK / 8) + (int)(blockIdx.x >> 3);
    int bi, bj;
    decode_tile(t, bi, bj);
    const int R0 = bi * 128, C0 = bj * 128;
    const int wr = wave >> 1, wc = wave & 1;
    f32x4 acc[4][4];
    #pragma unroll
    for (int r = 0; r < 4; ++r)
        #pragma unroll
        for (int c = 0; c < 4; ++c) acc[r][c] = (f32x4){0.f, 0.f, 0.f, 0.f};
    mm_kloop16(zn + (size_t)R0 * DIM, DIM, zn + (size_t)C0 * DIM, DIM, As, Bs, acc, wave, lane);

    // fused exp epilogue (stored element covers (j,i) [j-stats] and, off-diag, (i,j) [i-stats])
    int labj[4]; float muj[4], isj[4];
    #pragma unroll
    for (int c = 0; c < 4; ++c) {
        const int j = C0 + wc * 64 + c * 16 + f_l;
        labj[c] = labels[j]; muj[c] = mu_d[j]; isj[c] = inv2s2[j];
    }
    float local = 0.f;
    #pragma unroll
    for (int r = 0; r < 4; ++r) {
        const int ib = R0 + wr * 64 + r * 16 + q_l * 4;
        #pragma unroll
        for (int u = 0; u < 4; ++u) {
            const int   li = labels[ib + u];
            const float mi = mu_d[ib + u];
            const float vi = inv2s2[ib + u];
            #pragma unroll
            for (int c = 0; c < 4; ++c) {
                const float s  = acc[r][c][u];
                const float dj = (1.0f - s) - muj[c];
                float e = __expf(s * TEMP_INV + dj * dj * isj[c]);
                if (bi != bj) {
                    const float di = (1.0f - s) - mi;
                    e += __expf(s * TEMP_INV + di * di * vi);
                }
                local += (li != labj[c]) ? e : 0.f;
            }
        }
    }
    #pragma unroll
    for (int off = 1; off < 64; off <<= 1) local += __shfl_xor(local, off);
    if (lane == 0) redbuf[wave] = local;
    __syncthreads();
    if (tid == 0)
        atomicAdd(neg_acc, (double)(redbuf[0] + redbuf[1] + redbuf[2] + redbuf[3]));
}

// ---------------- positive pairs (vectorized) ----------------
__global__ __launch_bounds__(256)
void pos_k(const __hip_bfloat16* __restrict__ zn, const int* __restrict__ labels,
           double* __restrict__ pos_acc)
{
    const int wave = threadIdx.x >> 6, lane = threadIdx.x & 63;
    const int pair = blockIdx.x * 4 + wave;
    const bf16x8 va = *(const bf16x8*)(zn + (size_t)pair * DIM + lane * 8);
    const bf16x8 vb = *(const bf16x8*)(zn + (size_t)(pair + BATCH) * DIM + lane * 8);
    float s = 0.f;
    #pragma unroll
    for (int j = 0; j < 8; ++j)
        s += b2f((unsigned short)va[j]) * b2f((unsigned short)vb[j]);
    #pragma unroll
    for (int off = 1; off < 64; off <<= 1) s += __shfl_xor(s, off);
    if (lane == 0 && labels[pair] == labels[pair + BATCH])
        atomicAdd(pos_acc, (double)__expf(s * TEMP_INV));
}

// ---------------- final loss ----------------
__global__ void loss_k(const double* __restrict__ accs, float* __restrict__ out)
{
    const double neg = accs[0], pos = accs[1];
    out[0] = (float)(-log(pos / (pos + neg)));
}

extern "C" void kernel_launch(void* const* d_in, const int* in_sizes, int n_in,
                              void* d_out, int out_size, void* d_ws, size_t ws_size,
                              hipStream_t stream)
{
    const float* z      = (const float*)d_in[0];
    const int*   labels = (const int*)d_in[1];
    float* out = (float*)d_out;

    char* ws = (char*)d_ws;
    __hip_bfloat16* zn  = (__hip_bfloat16*)ws;                                // 8 MiB
    __hip_bfloat16* znT = (__hip_bfloat16*)(ws + ((size_t)8 << 20));          // 8 MiB
    float*  Gpart   = (float*)(ws + ((size_t)16 << 20));                      // 16 MiB (16 x 1 MiB)
    float*  S        = (float*)(ws + ((size_t)32 << 20));                     // 2 KiB
    float*  rowsumsq = S + 512;                                               // 32 KiB
    double* accs     = (double*)(rowsumsq + NTOT);                            // 16 B  [0]=neg [1]=pos
    float*  mu_d     = (float*)(accs + 2);                                    // 32 KiB
    float*  inv2s2   = mu_d + NTOT;                                           // 32 KiB
    __hip_bfloat16* G1 = (__hip_bfloat16*)(inv2s2 + NTOT);                    // 512 KiB

    // zero: S + rowsumsq + accs (contiguous)
    hipMemsetAsync(S, 0, (size_t)(512 + NTOT) * sizeof(float) + 2 * sizeof(double), stream);

    normalize_k<<<NTOT / 4, 256, 0, stream>>>(z, zn);
    transpose_colsum_k<<<1024, 256, 0, stream>>>(zn, znT, S);
    gram_k<<<256, 256, 0, stream>>>(znT, Gpart);
    gram_fin_k<<<256, 256, 0, stream>>>(Gpart, G1);
    rowstats_k<<<256, 256, 0, stream>>>(zn, G1, rowsumsq);
    finalize_stats_k<<<NTOT / 4, 256, 0, stream>>>(zn, S, rowsumsq, mu_d, inv2s2);
    sim_neg_k<<<NBLK, 256, 0, stream>>>(zn, labels, mu_d, inv2s2, accs);
    pos_k<<<BATCH / 4, 256, 0, stream>>>(zn, labels, accs + 1);
    loss_k<<<1, 1, 0, stream>>>(accs, out);
}

// Round 3
// 225.562 us; speedup vs baseline: 1.0286x; 1.0112x over previous
//
#include <hip/hip_runtime.h>
#include <hip/hip_bf16.h>
#include <math.h>

#define NTOT  8192
#define DIM   512
#define BATCH (NTOT/2)
#define TEMP_INV 5.0f   // 1/0.2
#define TTILE 64                      // 8192 / 128 tiles per side
#define NBLK  (TTILE*(TTILE+1)/2)     // 2080 upper-triangle tiles
#define GCH   32                      // gram K-chunks (256 samples each)

typedef __attribute__((ext_vector_type(8))) short bf16x8;
typedef __attribute__((ext_vector_type(4))) float f32x4;

__device__ __forceinline__ float b2f(unsigned short u)
{
    unsigned int x = (unsigned int)u << 16;
    float f; __builtin_memcpy(&f, &x, 4); return f;
}

// column-major triangle decode: t = bj*(bj+1)/2 + bi, bi <= bj.
__device__ __forceinline__ void decode_tile(int t, int& bi, int& bj)
{
    int b = (int)((sqrtf(8.0f * (float)t + 1.0f) - 1.0f) * 0.5f);
    while ((b + 1) * (b + 2) / 2 <= t) ++b;
    while (b * (b + 1) / 2 > t)       --b;
    bj = b;
    bi = t - b * (b + 1) / 2;
}

__device__ __forceinline__ unsigned int pack_bf16_2(float a, float b)
{
    __hip_bfloat16 ha = __float2bfloat16(a), hb = __float2bfloat16(b);
    unsigned short ua, ub;
    __builtin_memcpy(&ua, &ha, 2); __builtin_memcpy(&ub, &hb, 2);
    return (unsigned int)ua | ((unsigned int)ub << 16);
}

// ---------------- normalize: one wave per row ----------------
__global__ __launch_bounds__(256)
void normalize_k(const float* __restrict__ z, __hip_bfloat16* __restrict__ zn)
{
    const int lane = threadIdx.x & 63, wave = threadIdx.x >> 6;
    const int row  = blockIdx.x * 4 + wave;
    const float4* zr = (const float4*)(z + (size_t)row * DIM);
    const float4 a = zr[lane];
    const float4 b = zr[lane + 64];
    float ss = a.x*a.x + a.y*a.y + a.z*a.z + a.w*a.w
             + b.x*b.x + b.y*b.y + b.z*b.z + b.w*b.w;
    #pragma unroll
    for (int off = 1; off < 64; off <<= 1) ss += __shfl_xor(ss, off);
    const float inv = 1.0f / fmaxf(sqrtf(ss), 1e-12f);
    uint2* zo = (uint2*)(zn + (size_t)row * DIM);
    uint2 o0, o1;
    o0.x = pack_bf16_2(a.x * inv, a.y * inv);
    o0.y = pack_bf16_2(a.z * inv, a.w * inv);
    o1.x = pack_bf16_2(b.x * inv, b.y * inv);
    o1.y = pack_bf16_2(b.z * inv, b.w * inv);
    zo[lane]      = o0;
    zo[lane + 64] = o1;
}

// ---------------- transpose zn -> znT [512][8192], fused column sums S ----------------
__global__ __launch_bounds__(256)
void transpose_colsum_k(const __hip_bfloat16* __restrict__ zn,
                        __hip_bfloat16* __restrict__ znT,
                        float* __restrict__ S)
{
    __shared__ unsigned short T[64][72];   // 72-short row stride = 144 B (16 B aligned)
    __shared__ float Scol[64];
    const int tid = threadIdx.x;
    const int bs = blockIdx.x & 127;       // sample tile (8192/64)
    const int bd = blockIdx.x >> 7;        // dim tile (512/64)
    const int s0 = bs * 64, d0 = bd * 64;
    if (tid < 64) Scol[tid] = 0.f;
    const int rr = tid >> 3;               // 0..31
    const int c8 = (tid & 7) * 8;          // 0,8,..,56
    float part[8];
    #pragma unroll
    for (int j = 0; j < 8; ++j) part[j] = 0.f;
    #pragma unroll
    for (int h = 0; h < 2; ++h) {
        const int row = rr + h * 32;
        const bf16x8 v = *(const bf16x8*)(zn + (size_t)(s0 + row) * DIM + d0 + c8);
        *(bf16x8*)&T[row][c8] = v;
        #pragma unroll
        for (int j = 0; j < 8; ++j) part[j] += b2f((unsigned short)v[j]);
    }
    __syncthreads();
    #pragma unroll
    for (int h = 0; h < 2; ++h) {
        const int d = rr + h * 32;
        bf16x8 ov;
        #pragma unroll
        for (int j = 0; j < 8; ++j) ov[j] = (short)T[c8 + j][d];
        *(bf16x8*)(znT + (size_t)(d0 + d) * NTOT + s0 + c8) = ov;
    }
    #pragma unroll
    for (int j = 0; j < 8; ++j) atomicAdd(&Scol[c8 + j], part[j]);
    __syncthreads();
    if (tid < 64) atomicAdd(&S[d0 + tid], Scol[tid]);
}

// ---------------- shared MFMA K-loop: 128x128 tile, BK=32, NSTEP K-steps ----------------
// LDS: 3-stage ring, 2-deep prefetch, counted vmcnt, ONE barrier per K-step.
__device__ __forceinline__ void issue4(const __hip_bfloat16* A, int sA,
                                       const __hip_bfloat16* B, int sB,
                                       int gk, unsigned short* Ad, unsigned short* Bd,
                                       int wave, int lane)
{
    const int f_l = lane & 15, q_l = lane >> 4;
    #pragma unroll
    for (int q = 0; q < 2; ++q) {
        const int s = wave * 2 + q;
        const __hip_bfloat16* ga = A + (size_t)(s * 16 + f_l) * sA + gk + q_l * 8;
        const __hip_bfloat16* gb = B + (size_t)(s * 16 + f_l) * sB + gk + q_l * 8;
        __builtin_amdgcn_global_load_lds(
            (const __attribute__((address_space(1))) unsigned int*)ga,
            (__attribute__((address_space(3))) unsigned int*)(Ad + s * 512 + lane * 8),
            16, 0, 0);
        __builtin_amdgcn_global_load_lds(
            (const __attribute__((address_space(1))) unsigned int*)gb,
            (__attribute__((address_space(3))) unsigned int*)(Bd + s * 512 + lane * 8),
            16, 0, 0);
    }
}

template<int NSTEP>
__device__ __forceinline__ void mm_kloop(const __hip_bfloat16* A, int sA,
                                         const __hip_bfloat16* B, int sB,
                                         unsigned short (*As)[4096],
                                         unsigned short (*Bs)[4096],
                                         f32x4 acc[4][4], int wave, int lane)
{
    const int wr = wave >> 1, wc = wave & 1;
    issue4(A, sA, B, sB, 0,  As[0], Bs[0], wave, lane);
    issue4(A, sA, B, sB, 32, As[1], Bs[1], wave, lane);
    #pragma unroll
    for (int ki = 0; ki < NSTEP; ++ki) {
        // Wait: my 4 loads for buf[ki%3] done; next buf's 4 stay in flight.
        // Barrier then guarantees ALL waves' loads landed AND all waves finished
        // reading buf[(ki-1)%3] == buf[(ki+2)%3] -> safe to re-target it below.
        if (ki < NSTEP - 1) asm volatile("s_waitcnt vmcnt(4)\n\ts_barrier" ::: "memory");
        else                asm volatile("s_waitcnt vmcnt(0)\n\ts_barrier" ::: "memory");
        __builtin_amdgcn_sched_barrier(0);
        if (ki + 2 < NSTEP)
            issue4(A, sA, B, sB, (ki + 2) * 32, As[(ki + 2) % 3], Bs[(ki + 2) % 3], wave, lane);
        const unsigned short* Ap = As[ki % 3];
        const unsigned short* Bp = Bs[ki % 3];
        bf16x8 af[4], bfr[4];
        #pragma unroll
        for (int r = 0; r < 4; ++r)
            af[r] = *(const bf16x8*)(Ap + (wr * 4 + r) * 512 + lane * 8);
        #pragma unroll
        for (int c = 0; c < 4; ++c)
            bfr[c] = *(const bf16x8*)(Bp + (wc * 4 + c) * 512 + lane * 8);
        #pragma unroll
        for (int r = 0; r < 4; ++r)
            #pragma unroll
            for (int c = 0; c < 4; ++c)
                acc[r][c] = __builtin_amdgcn_mfma_f32_16x16x32_bf16(af[r], bfr[c], acc[r][c], 0, 0, 0);
    }
}

// ---------------- Gram: G = znT . znT^T = zn^T zn, per-chunk partials (NO atomics) ----------------
// grid = 16 tiles x GCH chunks (256 samples each) -> 512 blocks, 2/CU.
__global__ __launch_bounds__(256, 3)
void gram_k(const __hip_bfloat16* __restrict__ znT, float* __restrict__ Gpart)
{
    __shared__ unsigned short As[3][4096];
    __shared__ unsigned short Bs[3][4096];
    const int tid = threadIdx.x, wave = tid >> 6, lane = tid & 63;
    const int f_l = lane & 15, q_l = lane >> 4;
    const int t = blockIdx.x & 15, ch = blockIdx.x >> 4;
    const int di = (t >> 2) * 128, dj = (t & 3) * 128;
    const int wr = wave >> 1, wc = wave & 1;
    f32x4 acc[4][4];
    #pragma unroll
    for (int r = 0; r < 4; ++r)
        #pragma unroll
        for (int c = 0; c < 4; ++c) acc[r][c] = (f32x4){0.f, 0.f, 0.f, 0.f};
    mm_kloop<8>(znT + (size_t)di * NTOT + ch * 256, NTOT,
                znT + (size_t)dj * NTOT + ch * 256, NTOT, As, Bs, acc, wave, lane);
    float* gp = Gpart + (size_t)ch * (512 * 512);
    #pragma unroll
    for (int r = 0; r < 4; ++r)
        #pragma unroll
        for (int c = 0; c < 4; ++c)
            #pragma unroll
            for (int u = 0; u < 4; ++u) {
                const int row = di + wr * 64 + r * 16 + q_l * 4 + u;
                const int col = dj + wc * 64 + c * 16 + f_l;
                gp[row * 512 + col] = acc[r][c][u];
            }
}

// ---------------- reduce GCH partials -> bf16 G ----------------
__global__ __launch_bounds__(256)
void gram_fin_k(const float* __restrict__ Gpart, __hip_bfloat16* __restrict__ G1)
{
    const int i = (blockIdx.x * 256 + threadIdx.x) * 4;
    float4 s = {0.f, 0.f, 0.f, 0.f};
    #pragma unroll
    for (int ch = 0; ch < GCH; ++ch) {
        const float4 v = *(const float4*)(Gpart + (size_t)ch * (512 * 512) + i);
        s.x += v.x; s.y += v.y; s.z += v.z; s.w += v.w;
    }
    uint2 o;
    o.x = pack_bf16_2(s.x, s.y);
    o.y = pack_bf16_2(s.z, s.w);
    *(uint2*)(G1 + i) = o;
}

// ---------------- rowsumsq_i = zn_i G zn_i^T via H = zn.G, split-K, fused reduce ----------------
// grid = 64 R-blocks x 4 C-blocks x 2 K-halves -> 512 blocks, 2/CU.
__global__ __launch_bounds__(256, 3)
void rowstats_k(const __hip_bfloat16* __restrict__ zn,
                const __hip_bfloat16* __restrict__ G1,
                float* __restrict__ rowsumsq)
{
    __shared__ unsigned short As[3][4096];
    __shared__ unsigned short Bs[3][4096];
    const int tid = threadIdx.x, wave = tid >> 6, lane = tid & 63;
    const int f_l = lane & 15, q_l = lane >> 4;
    const int R0 = (blockIdx.x >> 3) * 128;
    const int C0 = ((blockIdx.x >> 1) & 3) * 128;
    const int kh = (blockIdx.x & 1) * 256;
    const int wr = wave >> 1, wc = wave & 1;
    f32x4 acc[4][4];
    #pragma unroll
    for (int r = 0; r < 4; ++r)
        #pragma unroll
        for (int c = 0; c < 4; ++c) acc[r][c] = (f32x4){0.f, 0.f, 0.f, 0.f};
    mm_kloop<8>(zn + (size_t)R0 * DIM + kh, DIM, G1 + (size_t)C0 * DIM + kh, DIM,
                As, Bs, acc, wave, lane);
    #pragma unroll
    for (int r = 0; r < 4; ++r) {
        #pragma unroll
        for (int u = 0; u < 4; ++u) {
            const int i = R0 + wr * 64 + r * 16 + q_l * 4 + u;
            float p = 0.f;
            #pragma unroll
            for (int c = 0; c < 4; ++c) {
                const int col = C0 + wc * 64 + c * 16 + f_l;
                unsigned short zb;
                __builtin_memcpy(&zb, zn + (size_t)i * DIM + col, 2);
                p += acc[r][c][u] * b2f(zb);
            }
            p += __shfl_xor(p, 1); p += __shfl_xor(p, 2);
            p += __shfl_xor(p, 4); p += __shfl_xor(p, 8);
            if (f_l == 0) atomicAdd(&rowsumsq[i], p);
        }
    }
}

// ---------------- stats finalize, fused rowsum (zn_i . S) ----------------
__global__ __launch_bounds__(256)
void finalize_stats_k(const __hip_bfloat16* __restrict__ zn,
                      const float* __restrict__ S,
                      const float* __restrict__ rowsumsq,
                      float* __restrict__ mu_d,
                      float* __restrict__ inv2s2)
{
    const int lane = threadIdx.x & 63, wave = threadIdx.x >> 6;
    const int row = blockIdx.x * 4 + wave;
    const bf16x8 v = *(const bf16x8*)(zn + (size_t)row * DIM + lane * 8);
    const float4 sa = *(const float4*)(S + lane * 8);
    const float4 sb = *(const float4*)(S + lane * 8 + 4);
    float acc = b2f((unsigned short)v[0]) * sa.x + b2f((unsigned short)v[1]) * sa.y
              + b2f((unsigned short)v[2]) * sa.z + b2f((unsigned short)v[3]) * sa.w
              + b2f((unsigned short)v[4]) * sb.x + b2f((unsigned short)v[5]) * sb.y
              + b2f((unsigned short)v[6]) * sb.z + b2f((unsigned short)v[7]) * sb.w;
    #pragma unroll
    for (int off = 1; off < 64; off <<= 1) acc += __shfl_xor(acc, off);
    if (lane == 0) {
        const float s  = acc;
        const float sq = rowsumsq[row];
        const float mean_sim = s * (1.0f / NTOT);
        const float var = (sq - s * mean_sim) * (1.0f / (NTOT - 1));
        mu_d[row]   = 1.0f - mean_sim;
        inv2s2[row] = 1.0f / (2.0f * var);
    }
}

// ---------------- single fused pass: triangle GEMM + exp epilogue ----------------
__global__ __launch_bounds__(256, 3)
void sim_neg_k(const __hip_bfloat16* __restrict__ zn,
               const int*   __restrict__ labels,
               const float* __restrict__ mu_d,
               const float* __restrict__ inv2s2,
               double* __restrict__ neg_acc)
{
    __shared__ unsigned short As[3][4096];
    __shared__ unsigned short Bs[3][4096];
    __shared__ float redbuf[4];
    const int tid = threadIdx.x, wave = tid >> 6, lane = tid & 63;
    const int f_l = lane & 15, q_l = lane >> 4;
    // chunked XCD swizzle: 2080 % 8 == 0 -> bijective; each XCD gets 260 consecutive tiles
    const int t = (int)(blockIdx.x & 7) * (NBLK / 8) + (int)(blockIdx.x >> 3);
    int bi, bj;
    decode_tile(t, bi, bj);
    const int R0 = bi * 128, C0 = bj * 128;
    const int wr = wave >> 1, wc = wave & 1;
    f32x4 acc[4][4];
    #pragma unroll
    for (int r = 0; r < 4; ++r)
        #pragma unroll
        for (int c = 0; c < 4; ++c) acc[r][c] = (f32x4){0.f, 0.f, 0.f, 0.f};
    mm_kloop<16>(zn + (size_t)R0 * DIM, DIM, zn + (size_t)C0 * DIM, DIM, As, Bs, acc, wave, lane);

    // fused exp epilogue (stored element covers (j,i) [j-stats] and, off-diag, (i,j) [i-stats])
    int labj[4]; float muj[4], isj[4];
    #pragma unroll
    for (int c = 0; c < 4; ++c) {
        const int j = C0 + wc * 64 + c * 16 + f_l;
        labj[c] = labels[j]; muj[c] = mu_d[j]; isj[c] = inv2s2[j];
    }
    float local = 0.f;
    #pragma unroll
    for (int r = 0; r < 4; ++r) {
        const int ib = R0 + wr * 64 + r * 16 + q_l * 4;
        #pragma unroll
        for (int u = 0; u < 4; ++u) {
            const int   li = labels[ib + u];
            const float mi = mu_d[ib + u];
            const float vi = inv2s2[ib + u];
            #pragma unroll
            for (int c = 0; c < 4; ++c) {
                const float s  = acc[r][c][u];
                const float dj = (1.0f - s) - muj[c];
                float e = __expf(s * TEMP_INV + dj * dj * isj[c]);
                if (bi != bj) {
                    const float di = (1.0f - s) - mi;
                    e += __expf(s * TEMP_INV + di * di * vi);
                }
                local += (li != labj[c]) ? e : 0.f;
            }
        }
    }
    #pragma unroll
    for (int off = 1; off < 64; off <<= 1) local += __shfl_xor(local, off);
    if (lane == 0) redbuf[wave] = local;
    __syncthreads();
    if (tid == 0)
        atomicAdd(neg_acc, (double)(redbuf[0] + redbuf[1] + redbuf[2] + redbuf[3]));
}

// ---------------- positive pairs (vectorized) ----------------
__global__ __launch_bounds__(256)
void pos_k(const __hip_bfloat16* __restrict__ zn, const int* __restrict__ labels,
           double* __restrict__ pos_acc)
{
    const int wave = threadIdx.x >> 6, lane = threadIdx.x & 63;
    const int pair = blockIdx.x * 4 + wave;
    const bf16x8 va = *(const bf16x8*)(zn + (size_t)pair * DIM + lane * 8);
    const bf16x8 vb = *(const bf16x8*)(zn + (size_t)(pair + BATCH) * DIM + lane * 8);
    float s = 0.f;
    #pragma unroll
    for (int j = 0; j < 8; ++j)
        s += b2f((unsigned short)va[j]) * b2f((unsigned short)vb[j]);
    #pragma unroll
    for (int off = 1; off < 64; off <<= 1) s += __shfl_xor(s, off);
    if (lane == 0 && labels[pair] == labels[pair + BATCH])
        atomicAdd(pos_acc, (double)__expf(s * TEMP_INV));
}

// ---------------- final loss ----------------
__global__ void loss_k(const double* __restrict__ accs, float* __restrict__ out)
{
    const double neg = accs[0], pos = accs[1];
    out[0] = (float)(-log(pos / (pos + neg)));
}

extern "C" void kernel_launch(void* const* d_in, const int* in_sizes, int n_in,
                              void* d_out, int out_size, void* d_ws, size_t ws_size,
                              hipStream_t stream)
{
    const float* z      = (const float*)d_in[0];
    const int*   labels = (const int*)d_in[1];
    float* out = (float*)d_out;

    char* ws = (char*)d_ws;
    __hip_bfloat16* zn  = (__hip_bfloat16*)ws;                                // 8 MiB
    __hip_bfloat16* znT = (__hip_bfloat16*)(ws + ((size_t)8 << 20));          // 8 MiB
    float*  Gpart    = (float*)(ws + ((size_t)16 << 20));                     // GCH MiB
    float*  S        = (float*)(ws + ((size_t)(16 + GCH) << 20));             // 2 KiB
    float*  rowsumsq = S + 512;                                               // 32 KiB
    double* accs     = (double*)(rowsumsq + NTOT);                            // 16 B  [0]=neg [1]=pos
    float*  mu_d     = (float*)(accs + 2);                                    // 32 KiB
    float*  inv2s2   = mu_d + NTOT;                                           // 32 KiB
    __hip_bfloat16* G1 = (__hip_bfloat16*)(inv2s2 + NTOT);                    // 512 KiB

    // zero: S + rowsumsq + accs (contiguous)
    hipMemsetAsync(S, 0, (size_t)(512 + NTOT) * sizeof(float) + 2 * sizeof(double), stream);

    normalize_k<<<NTOT / 4, 256, 0, stream>>>(z, zn);
    transpose_colsum_k<<<1024, 256, 0, stream>>>(zn, znT, S);
    gram_k<<<16 * GCH, 256, 0, stream>>>(znT, Gpart);
    gram_fin_k<<<256, 256, 0, stream>>>(Gpart, G1);
    rowstats_k<<<512, 256, 0, stream>>>(zn, G1, rowsumsq);
    finalize_stats_k<<<NTOT / 4, 256, 0, stream>>>(zn, S, rowsumsq, mu_d, inv2s2);
    sim_neg_k<<<NBLK, 256, 0, stream>>>(zn, labels, mu_d, inv2s2, accs);
    pos_k<<<BATCH / 4, 256, 0, stream>>>(zn, labels, accs + 1);
    loss_k<<<1, 1, 0, stream>>>(accs, out);
}